// Round 11
// baseline (452.230 us; speedup 1.0000x reference)
//
#include <hip/hip_runtime.h>
#include <hip/hip_bf16.h>
#include <stdint.h>

#define GN 8192
#define GF 128
#define NEG_SLOPE 0.2f
#define LCAP 1024   // per-row kept-edge capacity (binomial mean 410, max ~510)

typedef __attribute__((ext_vector_type(4))) float f32x4;

__device__ __forceinline__ unsigned fkey(float f) {
    unsigned u = __float_as_uint(f);
    return (u & 0x80000000u) ? ~u : (u | 0x80000000u);
}
__device__ __forceinline__ float funkey(unsigned k) {
    unsigned b = (k & 0x80000000u) ? (k & 0x7FFFFFFFu) : ~k;
    return __uint_as_float(b);
}
__device__ __forceinline__ unsigned short bf16rne(float f) {
    unsigned u = __float_as_uint(f);
    return (unsigned short)((u + 0x7FFFu + ((u >> 16) & 1u)) >> 16);
}

// K1: x' = x@W + b (fp32); xp = bf16 x' ROW-MAJOR [node][feat]; s_src/s_dst.
__global__ __launch_bounds__(256) void gat_k1(
    const float* __restrict__ x, const float* __restrict__ w,
    const float* __restrict__ bias, const float* __restrict__ phi,
    unsigned short* __restrict__ xp, float* __restrict__ s_src,
    float* __restrict__ s_dst)
{
    __shared__ float Xl[16][132];
    __shared__ float Wl[32][132];
    const int tid = threadIdx.x;
    const int i0 = blockIdx.x * 16;

    #pragma unroll
    for (int q = 0; q < 2; q++) {                 // stage 16x128 x tile
        int flat = (q * 256 + tid) * 4;
        int r = flat >> 7, c = flat & 127;
        *(float4*)&Xl[r][c] = *(const float4*)&x[(size_t)(i0 + r) * GF + c];
    }

    const int rid = tid >> 5;          // 0..7 -> rows 2rid, 2rid+1
    const int c0  = (tid & 31) * 4;    // 4 consecutive features

    float acc[2][4] = {};
    for (int kc = 0; kc < 4; kc++) {   // W staged in 32-row chunks
        __syncthreads();
        #pragma unroll
        for (int q = 0; q < 4; q++) {
            int flat = (q * 256 + tid) * 4;
            int kk = flat >> 7, c = flat & 127;
            *(float4*)&Wl[kk][c] = *(const float4*)&w[(size_t)(kc * 32 + kk) * GF + c];
        }
        __syncthreads();
        #pragma unroll
        for (int k = 0; k < 32; k++) {
            float4 wv = *(const float4*)&Wl[k][c0];
            #pragma unroll
            for (int m = 0; m < 2; m++) {
                float xv = Xl[rid * 2 + m][kc * 32 + k];
                acc[m][0] = fmaf(xv, wv.x, acc[m][0]);
                acc[m][1] = fmaf(xv, wv.y, acc[m][1]);
                acc[m][2] = fmaf(xv, wv.z, acc[m][2]);
                acc[m][3] = fmaf(xv, wv.w, acc[m][3]);
            }
        }
    }

    float b4[4], p1[4], p2[4];
    #pragma unroll
    for (int q = 0; q < 4; q++) {
        b4[q] = bias[c0 + q];
        p1[q] = phi[c0 + q];
        p2[q] = phi[GF + c0 + q];
    }
    #pragma unroll
    for (int m = 0; m < 2; m++) {
        float ps = 0.f, pd = 0.f;
        unsigned short pk[4];
        #pragma unroll
        for (int q = 0; q < 4; q++) {
            float v = acc[m][q] + b4[q];
            ps = fmaf(v, p1[q], ps);
            pd = fmaf(v, p2[q], pd);
            pk[q] = bf16rne(v);
        }
        const int row = i0 + rid * 2 + m;
        *(ushort4*)&xp[(size_t)row * GF + c0] =
            make_ushort4(pk[0], pk[1], pk[2], pk[3]);
        #pragma unroll
        for (int s = 16; s >= 1; s >>= 1) {
            ps += __shfl_xor(ps, s, 64);
            pd += __shfl_xor(pd, s, 64);
        }
        if ((tid & 31) == 0) {
            s_src[row] = ps;
            s_dst[row] = pd;
        }
    }
}

// K1b: D = max(s_dst). 8 blocks -> only 8 same-address atomics.
__global__ __launch_bounds__(256) void gat_k1b(
    const float* __restrict__ s_dst, unsigned* __restrict__ Dkey)
{
    __shared__ float sm[4];
    const int tid = threadIdx.x;
    const int idx = (blockIdx.x * 256 + tid) * 4;
    float4 v = *(const float4*)&s_dst[idx];
    float m = fmaxf(fmaxf(v.x, v.y), fmaxf(v.z, v.w));
    #pragma unroll
    for (int s = 32; s >= 1; s >>= 1) m = fmaxf(m, __shfl_xor(m, s, 64));
    if ((tid & 63) == 0) sm[tid >> 6] = m;
    __syncthreads();
    if (tid == 0) {
        m = fmaxf(fmaxf(sm[0], sm[1]), fmaxf(sm[2], sm[3]));
        atomicMax(Dkey, fkey(m));
    }
}

// K2s: SPARSE flash GAT. adj is 5% dense -> compact kept columns per row,
// exp only on kept entries, gather-accumulate x'[j] from L2-resident bf16 xp.
// Block = 16 rows; wave w owns rows i0+4w..+3 end-to-end. NO barriers, no
// MFMA, no atomics; waves fully decoupled. adj streamed with 8 float4/lane
// register pipeline (8 KB/wave in flight). Per row:
//   1) compact: ballot keep=(a>0 || diag), mbcnt prefix -> jlist (LDS, u16)
//   2) batch: p = exp(lrelu(si+sd[j]) - Mi) for kept (7 wave-instrs), Z sum
//   3) gather: 2 edges/wave-instr (half-wave each, 4 feats/lane), unroll 4
__global__ __attribute__((amdgpu_waves_per_eu(2, 2)))
__launch_bounds__(256) void gat_k2s(
    const float* __restrict__ adj, const unsigned short* __restrict__ xp,
    const float* __restrict__ s_src, const float* __restrict__ s_dst,
    const unsigned* __restrict__ Dkey, float* __restrict__ out)
{
    __shared__ unsigned short jl[4][LCAP + 2];
    __shared__ float pl[4][LCAP + 2];

    const int tid  = threadIdx.x;
    const int wave = tid >> 6, lane = tid & 63;
    const int i0   = blockIdx.x * 16;
    unsigned short* jlist = jl[wave];
    float* plist = pl[wave];

    const float D = funkey(*Dkey);
    const int half = lane >> 5;          // gather: 0/1 = even/odd edge
    const int fl   = (lane & 31) * 4;    // gather: 4-feature base

    #pragma unroll 1
    for (int r = 0; r < 4; r++) {
        const int irow = i0 + wave * 4 + r;
        const float si = s_src[irow];
        const float t0 = si + D;
        const float mneg = -fmaxf(t0, NEG_SLOPE * t0);  // -Mi >= -(row max)
        const float* arow = adj + (size_t)irow * GN;

        // ---- 1) compact kept columns (streaming, 8-deep reg pipeline) ----
        int base = 0;
        float4 cur[8], na[8];
        #pragma unroll
        for (int k = 0; k < 8; k++)
            cur[k] = *(const float4*)(arow + k * 256 + lane * 4);

        #pragma unroll 1
        for (int sc = 0; sc < 4; sc++) {
            if (sc < 3) {   // prefetch next 2048-col superchunk
                #pragma unroll
                for (int k = 0; k < 8; k++)
                    na[k] = *(const float4*)(arow + (sc + 1) * 2048 + k * 256 + lane * 4);
            }
            #pragma unroll
            for (int k = 0; k < 8; k++) {
                const int cb = sc * 2048 + k * 256 + lane * 4;
                #pragma unroll
                for (int q = 0; q < 4; q++) {
                    const int j = cb + q;
                    const bool keep = ((&cur[k].x)[q] > 0.f) || (j == irow);
                    const unsigned long long m = __ballot(keep);
                    const int pre = __builtin_amdgcn_mbcnt_hi(
                        (unsigned)(m >> 32),
                        __builtin_amdgcn_mbcnt_lo((unsigned)m, 0));
                    if (keep) jlist[base + pre] = (unsigned short)j;
                    base += __popcll(m);
                }
            }
            if (sc < 3) {
                #pragma unroll
                for (int k = 0; k < 8; k++) cur[k] = na[k];
            }
        }
        const int len = base;

        // ---- 2) batch: sd gather + exp + Z ----
        float zacc = 0.f;
        for (int kb = 0; kb < len; kb += 64) {
            const int idx = kb + lane;
            float p = 0.f;
            if (idx < len) {
                const int j = jlist[idx];
                const float zz = si + s_dst[j];
                const float lr = fmaxf(zz, NEG_SLOPE * zz);
                p = __expf(lr + mneg);
                plist[idx] = p;
            }
            zacc += p;
        }
        if (lane == 0 && (len & 1)) {    // pad to even edge count
            jlist[len] = 0;
            plist[len] = 0.f;
        }
        #pragma unroll
        for (int s = 1; s <= 32; s <<= 1) zacc += __shfl_xor(zacc, s, 64);
        const float invz = 1.0f / zacc;

        // ---- 3) gather-accumulate: 2 edges per wave-instr ----
        const int len2 = len + (len & 1);
        f32x4 acc = {0.f, 0.f, 0.f, 0.f};
        #pragma unroll 4
        for (int e = 0; e < len2; e += 2) {
            const int eb = e + half;
            const int j = jlist[eb];                 // 2-addr LDS broadcast
            const float p = plist[eb];
            const uint2 u = *(const uint2*)&xp[(size_t)j * GF + fl];
            acc[0] = fmaf(p, __uint_as_float(u.x << 16), acc[0]);
            acc[1] = fmaf(p, __uint_as_float(u.x & 0xFFFF0000u), acc[1]);
            acc[2] = fmaf(p, __uint_as_float(u.y << 16), acc[2]);
            acc[3] = fmaf(p, __uint_as_float(u.y & 0xFFFF0000u), acc[3]);
        }

        // combine even/odd halves; lanes 0-31 hold all 128 feats
        #pragma unroll
        for (int i = 0; i < 4; i++) acc[i] += __shfl_xor(acc[i], 32, 64);
        if (lane < 32) {
            f32x4 o;
            #pragma unroll
            for (int i = 0; i < 4; i++) o[i] = acc[i] * invz;
            *(f32x4*)&out[(size_t)irow * GF + fl] = o;
        }
    }
}

extern "C" void kernel_launch(void* const* d_in, const int* in_sizes, int n_in,
                              void* d_out, int out_size, void* d_ws, size_t ws_size,
                              hipStream_t stream)
{
    (void)in_sizes; (void)n_in; (void)out_size; (void)ws_size;
    const float* adj  = (const float*)d_in[0];
    const float* x    = (const float*)d_in[1];
    const float* w    = (const float*)d_in[2];
    const float* bias = (const float*)d_in[3];
    const float* phi  = (const float*)d_in[4];
    float* out = (float*)d_out;

    char* ws = (char*)d_ws;
    unsigned short* xp = (unsigned short*)ws;              // 2 MB bf16 x' row-major
    float* s_src = (float*)(ws + (size_t)GF * GN * 2);     // 32 KB
    float* s_dst = s_src + GN;                             // 32 KB
    unsigned* Dkey = (unsigned*)(s_dst + GN);              // 4 B

    hipMemsetAsync(Dkey, 0, sizeof(unsigned), stream);
    gat_k1 <<<GN / 16, 256, 0, stream>>>(x, w, bias, phi, xp, s_src, s_dst);
    gat_k1b<<<8, 256, 0, stream>>>(s_dst, Dkey);
    gat_k2s<<<GN / 16, 256, 0, stream>>>(adj, xp, s_src, s_dst, Dkey, out);
}

// Round 12
// 422.763 us; speedup vs baseline: 1.0697x; 1.0697x over previous
//
#include <hip/hip_runtime.h>
#include <hip/hip_bf16.h>
#include <stdint.h>

#define GN 8192
#define GF 128
#define NEG_SLOPE 0.2f
#define LCAP 640    // kept edges/row: binomial(8192,.05) mean 410, +diag, max ~510

typedef __attribute__((ext_vector_type(4))) float f32x4;

__device__ __forceinline__ unsigned fkey(float f) {
    unsigned u = __float_as_uint(f);
    return (u & 0x80000000u) ? ~u : (u | 0x80000000u);
}
__device__ __forceinline__ float funkey(unsigned k) {
    unsigned b = (k & 0x80000000u) ? (k & 0x7FFFFFFFu) : ~k;
    return __uint_as_float(b);
}
__device__ __forceinline__ unsigned short bf16rne(float f) {
    unsigned u = __float_as_uint(f);
    return (unsigned short)((u + 0x7FFFu + ((u >> 16) & 1u)) >> 16);
}

// K1: x' = x@W + b (fp32); xp = bf16 x' ROW-MAJOR [node][feat]; s_src/s_dst.
__global__ __launch_bounds__(256) void gat_k1(
    const float* __restrict__ x, const float* __restrict__ w,
    const float* __restrict__ bias, const float* __restrict__ phi,
    unsigned short* __restrict__ xp, float* __restrict__ s_src,
    float* __restrict__ s_dst)
{
    __shared__ float Xl[16][132];
    __shared__ float Wl[32][132];
    const int tid = threadIdx.x;
    const int i0 = blockIdx.x * 16;

    #pragma unroll
    for (int q = 0; q < 2; q++) {                 // stage 16x128 x tile
        int flat = (q * 256 + tid) * 4;
        int r = flat >> 7, c = flat & 127;
        *(float4*)&Xl[r][c] = *(const float4*)&x[(size_t)(i0 + r) * GF + c];
    }

    const int rid = tid >> 5;          // 0..7 -> rows 2rid, 2rid+1
    const int c0  = (tid & 31) * 4;    // 4 consecutive features

    float acc[2][4] = {};
    for (int kc = 0; kc < 4; kc++) {   // W staged in 32-row chunks
        __syncthreads();
        #pragma unroll
        for (int q = 0; q < 4; q++) {
            int flat = (q * 256 + tid) * 4;
            int kk = flat >> 7, c = flat & 127;
            *(float4*)&Wl[kk][c] = *(const float4*)&w[(size_t)(kc * 32 + kk) * GF + c];
        }
        __syncthreads();
        #pragma unroll
        for (int k = 0; k < 32; k++) {
            float4 wv = *(const float4*)&Wl[k][c0];
            #pragma unroll
            for (int m = 0; m < 2; m++) {
                float xv = Xl[rid * 2 + m][kc * 32 + k];
                acc[m][0] = fmaf(xv, wv.x, acc[m][0]);
                acc[m][1] = fmaf(xv, wv.y, acc[m][1]);
                acc[m][2] = fmaf(xv, wv.z, acc[m][2]);
                acc[m][3] = fmaf(xv, wv.w, acc[m][3]);
            }
        }
    }

    float b4[4], p1[4], p2[4];
    #pragma unroll
    for (int q = 0; q < 4; q++) {
        b4[q] = bias[c0 + q];
        p1[q] = phi[c0 + q];
        p2[q] = phi[GF + c0 + q];
    }
    #pragma unroll
    for (int m = 0; m < 2; m++) {
        float ps = 0.f, pd = 0.f;
        unsigned short pk[4];
        #pragma unroll
        for (int q = 0; q < 4; q++) {
            float v = acc[m][q] + b4[q];
            ps = fmaf(v, p1[q], ps);
            pd = fmaf(v, p2[q], pd);
            pk[q] = bf16rne(v);
        }
        const int row = i0 + rid * 2 + m;
        *(ushort4*)&xp[(size_t)row * GF + c0] =
            make_ushort4(pk[0], pk[1], pk[2], pk[3]);
        #pragma unroll
        for (int s = 16; s >= 1; s >>= 1) {
            ps += __shfl_xor(ps, s, 64);
            pd += __shfl_xor(pd, s, 64);
        }
        if ((tid & 31) == 0) {
            s_src[row] = ps;
            s_dst[row] = pd;
        }
    }
}

// K1b: D = max(s_dst). 8 blocks -> only 8 same-address atomics.
__global__ __launch_bounds__(256) void gat_k1b(
    const float* __restrict__ s_dst, unsigned* __restrict__ Dkey)
{
    __shared__ float sm[4];
    const int tid = threadIdx.x;
    const int idx = (blockIdx.x * 256 + tid) * 4;
    float4 v = *(const float4*)&s_dst[idx];
    float m = fmaxf(fmaxf(v.x, v.y), fmaxf(v.z, v.w));
    #pragma unroll
    for (int s = 32; s >= 1; s >>= 1) m = fmaxf(m, __shfl_xor(m, s, 64));
    if ((tid & 63) == 0) sm[tid >> 6] = m;
    __syncthreads();
    if (tid == 0) {
        m = fmaxf(fmaxf(sm[0], sm[1]), fmaxf(sm[2], sm[3]));
        atomicMax(Dkey, fkey(m));
    }
}

// K2s: sparse GAT, fused compact+exp, batched gather.
// Block = 8 rows, 4 waves; wave owns 2 rows end-to-end. No barriers/atomics.
// Per row: (1) stream adj (8-deep float4 pipeline, coalesced 1KB/instr),
// ballot+mbcnt compact kept (j, p=exp(lrelu(si+sd)-Mi)) pairs into LDS as
// uint2; Z summed in registers. (2) gather: 16 edges/step — 8 independent
// ds_read_b64 (pair broadcast per half-wave) then 8 independent dwordx2
// gathers of bf16 x'[j] (L2-resident), 32 FMA. Grid 1024 -> 4 blocks/CU.
__global__ __attribute__((amdgpu_waves_per_eu(4, 4)))
__launch_bounds__(256) void gat_k2s(
    const float* __restrict__ adj, const unsigned short* __restrict__ xp,
    const float* __restrict__ s_src, const float* __restrict__ s_dst,
    const unsigned* __restrict__ Dkey, float* __restrict__ out)
{
    __shared__ uint2 ep[4][LCAP];    // (j, p-bits) per kept edge, per wave

    const int tid  = threadIdx.x;
    const int wave = tid >> 6, lane = tid & 63;
    const int i0   = blockIdx.x * 8;
    uint2* epw = ep[wave];

    const float D = funkey(*Dkey);
    const int half = lane >> 5;          // gather: 0/1 = even/odd edge of pair
    const int fl   = (lane & 31) * 4;    // gather: 4-feature base

    #pragma unroll 1
    for (int r = 0; r < 2; r++) {
        const int irow = i0 + wave * 2 + r;
        const float si = s_src[irow];
        const float t0 = si + D;
        const float mneg = -fmaxf(t0, NEG_SLOPE * t0);  // -Mi >= -(row max)
        const float* arow = adj + (size_t)irow * GN;

        // ---- 1) fused compact + exp (streaming, 8-deep reg pipeline) ----
        int base = 0;
        float zacc = 0.f;
        float4 cur[8], na[8];
        #pragma unroll
        for (int k = 0; k < 8; k++)
            cur[k] = *(const float4*)(arow + k * 256 + lane * 4);

        #pragma unroll 1
        for (int sc = 0; sc < 4; sc++) {
            if (sc < 3) {   // prefetch next 2048-col superchunk
                #pragma unroll
                for (int k = 0; k < 8; k++)
                    na[k] = *(const float4*)(arow + (sc + 1) * 2048 + k * 256 + lane * 4);
            }
            #pragma unroll
            for (int k = 0; k < 8; k++) {
                const int cb = sc * 2048 + k * 256 + lane * 4;
                const float4 a = cur[k];
                const float4 sd = *(const float4*)(s_dst + cb);  // L1-hot
                #pragma unroll
                for (int q = 0; q < 4; q++) {
                    const int j = cb + q;
                    const bool keep = ((&a.x)[q] > 0.f) || (j == irow);
                    const float tt = si + (&sd.x)[q];
                    const float lr = fmaxf(tt, NEG_SLOPE * tt);
                    const float p = __expf(lr + mneg);
                    const unsigned long long m = __ballot(keep);
                    const int pre = __builtin_amdgcn_mbcnt_hi(
                        (unsigned)(m >> 32),
                        __builtin_amdgcn_mbcnt_lo((unsigned)m, 0));
                    if (keep) {
                        epw[base + pre] = make_uint2((unsigned)j, __float_as_uint(p));
                        zacc += p;
                    }
                    base += (int)__popcll(m);
                }
            }
            if (sc < 3) {
                #pragma unroll
                for (int k = 0; k < 8; k++) cur[k] = na[k];
            }
        }
        int len = base;
        {   // pad to multiple of 16 with p=0 edges
            const int pad = (16 - (len & 15)) & 15;
            if (lane < pad) epw[len + lane] = make_uint2(0u, 0u);
            len += pad;
        }

        #pragma unroll
        for (int s = 1; s <= 32; s <<= 1) zacc += __shfl_xor(zacc, s, 64);
        const float invz = 1.0f / zacc;

        // ---- 2) batched gather-accumulate: 16 edges per step ----
        f32x4 acc = {0.f, 0.f, 0.f, 0.f};
        #pragma unroll 1
        for (int e = 0; e < len; e += 16) {
            uint2 pr[8];
            #pragma unroll
            for (int k = 0; k < 8; k++)          // 8 independent pair reads
                pr[k] = epw[e + k * 2 + half];
            uint2 u[8];
            #pragma unroll
            for (int k = 0; k < 8; k++)          // 8 independent L2 gathers
                u[k] = *(const uint2*)&xp[(size_t)pr[k].x * GF + fl];
            #pragma unroll
            for (int k = 0; k < 8; k++) {
                const float p = __uint_as_float(pr[k].y);
                acc[0] = fmaf(p, __uint_as_float(u[k].x << 16), acc[0]);
                acc[1] = fmaf(p, __uint_as_float(u[k].x & 0xFFFF0000u), acc[1]);
                acc[2] = fmaf(p, __uint_as_float(u[k].y << 16), acc[2]);
                acc[3] = fmaf(p, __uint_as_float(u[k].y & 0xFFFF0000u), acc[3]);
            }
        }

        // combine even/odd halves; lanes 0-31 hold all 128 feats
        #pragma unroll
        for (int i2 = 0; i2 < 4; i2++) acc[i2] += __shfl_xor(acc[i2], 32, 64);
        if (lane < 32) {
            f32x4 o;
            #pragma unroll
            for (int i2 = 0; i2 < 4; i2++) o[i2] = acc[i2] * invz;
            *(f32x4*)&out[(size_t)irow * GF + fl] = o;
        }
    }
}

extern "C" void kernel_launch(void* const* d_in, const int* in_sizes, int n_in,
                              void* d_out, int out_size, void* d_ws, size_t ws_size,
                              hipStream_t stream)
{
    (void)in_sizes; (void)n_in; (void)out_size; (void)ws_size;
    const float* adj  = (const float*)d_in[0];
    const float* x    = (const float*)d_in[1];
    const float* w    = (const float*)d_in[2];
    const float* bias = (const float*)d_in[3];
    const float* phi  = (const float*)d_in[4];
    float* out = (float*)d_out;

    char* ws = (char*)d_ws;
    unsigned short* xp = (unsigned short*)ws;              // 2 MB bf16 x' row-major
    float* s_src = (float*)(ws + (size_t)GF * GN * 2);     // 32 KB
    float* s_dst = s_src + GN;                             // 32 KB
    unsigned* Dkey = (unsigned*)(s_dst + GN);              // 4 B

    hipMemsetAsync(Dkey, 0, sizeof(unsigned), stream);
    gat_k1 <<<GN / 16, 256, 0, stream>>>(x, w, bias, phi, xp, s_src, s_dst);
    gat_k1b<<<8, 256, 0, stream>>>(s_dst, Dkey);
    gat_k2s<<<GN / 8, 256, 0, stream>>>(adj, xp, s_src, s_dst, Dkey, out);
}

// Round 13
// 417.894 us; speedup vs baseline: 1.0822x; 1.0117x over previous
//
#include <hip/hip_runtime.h>
#include <hip/hip_bf16.h>
#include <stdint.h>

#define GN 8192
#define GF 128
#define NEG_SLOPE 0.2f
#define LCAP 640    // kept edges/row: binomial(8192,.05) mean 410+diag, max ~500

typedef __attribute__((ext_vector_type(4))) float f32x4;

__device__ __forceinline__ unsigned fkey(float f) {
    unsigned u = __float_as_uint(f);
    return (u & 0x80000000u) ? ~u : (u | 0x80000000u);
}
__device__ __forceinline__ float funkey(unsigned k) {
    unsigned b = (k & 0x80000000u) ? (k & 0x7FFFFFFFu) : ~k;
    return __uint_as_float(b);
}
__device__ __forceinline__ unsigned short bf16rne(float f) {
    unsigned u = __float_as_uint(f);
    return (unsigned short)((u + 0x7FFFu + ((u >> 16) & 1u)) >> 16);
}

// K1: x' = x@W + b (fp32); xp = bf16 x' ROW-MAJOR [node][feat]; s_src/s_dst.
__global__ __launch_bounds__(256) void gat_k1(
    const float* __restrict__ x, const float* __restrict__ w,
    const float* __restrict__ bias, const float* __restrict__ phi,
    unsigned short* __restrict__ xp, float* __restrict__ s_src,
    float* __restrict__ s_dst)
{
    __shared__ float Xl[16][132];
    __shared__ float Wl[32][132];
    const int tid = threadIdx.x;
    const int i0 = blockIdx.x * 16;

    #pragma unroll
    for (int q = 0; q < 2; q++) {                 // stage 16x128 x tile
        int flat = (q * 256 + tid) * 4;
        int r = flat >> 7, c = flat & 127;
        *(float4*)&Xl[r][c] = *(const float4*)&x[(size_t)(i0 + r) * GF + c];
    }

    const int rid = tid >> 5;          // 0..7 -> rows 2rid, 2rid+1
    const int c0  = (tid & 31) * 4;    // 4 consecutive features

    float acc[2][4] = {};
    for (int kc = 0; kc < 4; kc++) {   // W staged in 32-row chunks
        __syncthreads();
        #pragma unroll
        for (int q = 0; q < 4; q++) {
            int flat = (q * 256 + tid) * 4;
            int kk = flat >> 7, c = flat & 127;
            *(float4*)&Wl[kk][c] = *(const float4*)&w[(size_t)(kc * 32 + kk) * GF + c];
        }
        __syncthreads();
        #pragma unroll
        for (int k = 0; k < 32; k++) {
            float4 wv = *(const float4*)&Wl[k][c0];
            #pragma unroll
            for (int m = 0; m < 2; m++) {
                float xv = Xl[rid * 2 + m][kc * 32 + k];
                acc[m][0] = fmaf(xv, wv.x, acc[m][0]);
                acc[m][1] = fmaf(xv, wv.y, acc[m][1]);
                acc[m][2] = fmaf(xv, wv.z, acc[m][2]);
                acc[m][3] = fmaf(xv, wv.w, acc[m][3]);
            }
        }
    }

    float b4[4], p1[4], p2[4];
    #pragma unroll
    for (int q = 0; q < 4; q++) {
        b4[q] = bias[c0 + q];
        p1[q] = phi[c0 + q];
        p2[q] = phi[GF + c0 + q];
    }
    #pragma unroll
    for (int m = 0; m < 2; m++) {
        float ps = 0.f, pd = 0.f;
        unsigned short pk[4];
        #pragma unroll
        for (int q = 0; q < 4; q++) {
            float v = acc[m][q] + b4[q];
            ps = fmaf(v, p1[q], ps);
            pd = fmaf(v, p2[q], pd);
            pk[q] = bf16rne(v);
        }
        const int row = i0 + rid * 2 + m;
        *(ushort4*)&xp[(size_t)row * GF + c0] =
            make_ushort4(pk[0], pk[1], pk[2], pk[3]);
        #pragma unroll
        for (int s = 16; s >= 1; s >>= 1) {
            ps += __shfl_xor(ps, s, 64);
            pd += __shfl_xor(pd, s, 64);
        }
        if ((tid & 31) == 0) {
            s_src[row] = ps;
            s_dst[row] = pd;
        }
    }
}

// K1b: D = max(s_dst). 8 blocks -> only 8 same-address atomics.
__global__ __launch_bounds__(256) void gat_k1b(
    const float* __restrict__ s_dst, unsigned* __restrict__ Dkey)
{
    __shared__ float sm[4];
    const int tid = threadIdx.x;
    const int idx = (blockIdx.x * 256 + tid) * 4;
    float4 v = *(const float4*)&s_dst[idx];
    float m = fmaxf(fmaxf(v.x, v.y), fmaxf(v.z, v.w));
    #pragma unroll
    for (int s = 32; s >= 1; s >>= 1) m = fmaxf(m, __shfl_xor(m, s, 64));
    if ((tid & 63) == 0) sm[tid >> 6] = m;
    __syncthreads();
    if (tid == 0) {
        m = fmaxf(fmaxf(sm[0], sm[1]), fmaxf(sm[2], sm[3]));
        atomicMax(Dkey, fkey(m));
    }
}

// K2s: sparse GAT v3. Block = 8 rows, 4 waves; wave owns 2 rows end-to-end.
// s_dst staged in LDS (one barrier) so the streaming scan's ONLY VMEM is the
// adj stream -> the 8-deep float4 prefetch pipeline is never drained by a
// dependent global load (the r11/r12 vmcnt bug). Compaction stores (j, sd);
// exp runs only on kept entries (batch pass, ~7 wave-instrs/row); gather
// pulls 32 edges/step with 16 independent L2 gathers in flight.
__global__ __attribute__((amdgpu_waves_per_eu(3, 3)))
__launch_bounds__(256) void gat_k2s(
    const float* __restrict__ adj, const unsigned short* __restrict__ xp,
    const float* __restrict__ s_src, const float* __restrict__ s_dst,
    const unsigned* __restrict__ Dkey, float* __restrict__ out)
{
    __shared__ float sdl[GN];        // 32 KB: s_dst copy (lgkmcnt domain)
    __shared__ uint2 ep[4][LCAP];    // 20 KB: (j, sd->p bits) per wave

    const int tid  = threadIdx.x;
    const int wave = tid >> 6, lane = tid & 63;
    const int i0   = blockIdx.x * 8;
    uint2* epw = ep[wave];

    #pragma unroll
    for (int s = 0; s < 8; s++) {    // stage s_dst into LDS
        const int idx = (s * 256 + tid) * 4;
        *(float4*)&sdl[idx] = *(const float4*)&s_dst[idx];
    }
    __syncthreads();

    const float D = funkey(*Dkey);
    const int half = lane >> 5;          // gather: 0/1 = even/odd edge of pair
    const int fl   = (lane & 31) * 4;    // gather: 4-feature base

    #pragma unroll 1
    for (int r = 0; r < 2; r++) {
        const int irow = i0 + wave * 2 + r;
        const float si = s_src[irow];
        const float t0 = si + D;
        const float mneg = -fmaxf(t0, NEG_SLOPE * t0);  // -Mi >= -(row max)
        const float* arow = adj + (size_t)irow * GN;

        // ---- 1) compact kept (j, sd): adj-only VMEM, 8-deep pipeline ----
        int base = 0;
        float4 cur[8], na[8];
        #pragma unroll
        for (int k = 0; k < 8; k++)
            cur[k] = *(const float4*)(arow + k * 256 + lane * 4);

        #pragma unroll 1
        for (int sc = 0; sc < 4; sc++) {
            if (sc < 3) {   // prefetch next 2048-col superchunk (adj only)
                #pragma unroll
                for (int k = 0; k < 8; k++)
                    na[k] = *(const float4*)(arow + (sc + 1) * 2048 + k * 256 + lane * 4);
            }
            #pragma unroll
            for (int k = 0; k < 8; k++) {
                const int cb = sc * 2048 + k * 256 + lane * 4;
                const float4 a = cur[k];
                const float4 sd4 = *(const float4*)&sdl[cb];   // LDS, lgkm only
                #pragma unroll
                for (int q = 0; q < 4; q++) {
                    const int j = cb + q;
                    const bool keep = ((&a.x)[q] > 0.f) || (j == irow);
                    const unsigned long long m = __ballot(keep);
                    const int pre = __builtin_amdgcn_mbcnt_hi(
                        (unsigned)(m >> 32),
                        __builtin_amdgcn_mbcnt_lo((unsigned)m, 0));
                    if (keep)
                        epw[base + pre] =
                            make_uint2((unsigned)j, __float_as_uint((&sd4.x)[q]));
                    base += (int)__popcll(m);
                }
            }
            if (sc < 3) {
                #pragma unroll
                for (int k = 0; k < 8; k++) cur[k] = na[k];
            }
        }
        int len = base;
        {   // pad to multiple of 32 with exp->0 sentinels (sd = -3e8)
            const int pad = (32 - (len & 31)) & 31;
            if (lane < pad)
                epw[len + lane] = make_uint2(0u, __float_as_uint(-3.0e8f));
            len += pad;
        }

        // ---- 2) batch exp on kept entries only; write p back; Z in regs ----
        float zacc = 0.f;
        for (int kb = 0; kb < len; kb += 64) {
            const int idx = kb + lane;
            if (idx < len) {
                const uint2 e = epw[idx];
                const float tt = si + __uint_as_float(e.y);
                const float lr = fmaxf(tt, NEG_SLOPE * tt);
                const float p = __expf(lr + mneg);
                epw[idx].y = __float_as_uint(p);
                zacc += p;
            }
        }
        #pragma unroll
        for (int s = 1; s <= 32; s <<= 1) zacc += __shfl_xor(zacc, s, 64);
        const float invz = 1.0f / zacc;

        // ---- 3) gather-accumulate: 32 edges/step, 16 L2 gathers in flight ----
        f32x4 acc = {0.f, 0.f, 0.f, 0.f};
        #pragma unroll 1
        for (int e = 0; e < len; e += 32) {
            uint2 pr[16];
            #pragma unroll
            for (int k = 0; k < 16; k++)     // broadcast pair reads (LDS)
                pr[k] = epw[e + k * 2 + half];
            uint2 u[16];
            #pragma unroll
            for (int k = 0; k < 16; k++)     // independent L2 gathers
                u[k] = *(const uint2*)&xp[(size_t)pr[k].x * GF + fl];
            #pragma unroll
            for (int k = 0; k < 16; k++) {
                const float p = __uint_as_float(pr[k].y);
                acc[0] = fmaf(p, __uint_as_float(u[k].x << 16), acc[0]);
                acc[1] = fmaf(p, __uint_as_float(u[k].x & 0xFFFF0000u), acc[1]);
                acc[2] = fmaf(p, __uint_as_float(u[k].y << 16), acc[2]);
                acc[3] = fmaf(p, __uint_as_float(u[k].y & 0xFFFF0000u), acc[3]);
            }
        }

        // combine even/odd halves; lanes 0-31 hold all 128 feats
        #pragma unroll
        for (int i2 = 0; i2 < 4; i2++) acc[i2] += __shfl_xor(acc[i2], 32, 64);
        if (lane < 32) {
            f32x4 o;
            #pragma unroll
            for (int i2 = 0; i2 < 4; i2++) o[i2] = acc[i2] * invz;
            *(f32x4*)&out[(size_t)irow * GF + fl] = o;
        }
    }
}

extern "C" void kernel_launch(void* const* d_in, const int* in_sizes, int n_in,
                              void* d_out, int out_size, void* d_ws, size_t ws_size,
                              hipStream_t stream)
{
    (void)in_sizes; (void)n_in; (void)out_size; (void)ws_size;
    const float* adj  = (const float*)d_in[0];
    const float* x    = (const float*)d_in[1];
    const float* w    = (const float*)d_in[2];
    const float* bias = (const float*)d_in[3];
    const float* phi  = (const float*)d_in[4];
    float* out = (float*)d_out;

    char* ws = (char*)d_ws;
    unsigned short* xp = (unsigned short*)ws;              // 2 MB bf16 x' row-major
    float* s_src = (float*)(ws + (size_t)GF * GN * 2);     // 32 KB
    float* s_dst = s_src + GN;                             // 32 KB
    unsigned* Dkey = (unsigned*)(s_dst + GN);              // 4 B

    hipMemsetAsync(Dkey, 0, sizeof(unsigned), stream);
    gat_k1 <<<GN / 16, 256, 0, stream>>>(x, w, bias, phi, xp, s_src, s_dst);
    gat_k1b<<<8, 256, 0, stream>>>(s_dst, Dkey);
    gat_k2s<<<GN / 8, 256, 0, stream>>>(adj, xp, s_src, s_dst, Dkey, out);
}